// Round 8
// baseline (1100.524 us; speedup 1.0000x reference)
//
#include <hip/hip_runtime.h>
#include <hip/hip_bf16.h>

#define GN 200000
#define GB 10000
#define GE 600000
#define NCHUNK 98   // ceil(GN/2048)

typedef __bf16 bf16x8 __attribute__((ext_vector_type(8)));
typedef __bf16 bf16x2 __attribute__((ext_vector_type(2)));
typedef float  f32x4  __attribute__((ext_vector_type(4)));

__device__ inline float bfu2f(unsigned int u) {
    union { unsigned int i; float f; } c;
    c.i = u << 16;
    return c.f;
}

// async global->LDS, 16B per lane; lds dest = uniform base + lane*16
__device__ __forceinline__ void g2l16(const void* g, void* l) {
    __builtin_amdgcn_global_load_lds(
        (const __attribute__((address_space(1))) unsigned int*)g,
        (__attribute__((address_space(3))) unsigned int*)l, 16, 0, 0);
}

// ---------------- CSR construction (both graphs fused) ----------------
__global__ void deg2_kernel(const int* __restrict__ dst0, const int* __restrict__ dst1,
                            int* __restrict__ deg) {
    int e = blockIdx.x * 256 + threadIdx.x;
    if (e >= 2 * GE) return;
    int g = e >= GE ? 1 : 0;
    int ee = e - g * GE;
    const int* d = g ? dst1 : dst0;
    atomicAdd(&deg[g * GN + d[ee]], 1);
}

__global__ void scan1_kernel(int* __restrict__ data, int* __restrict__ csum) {
    __shared__ int ls[512];
    int b = blockIdx.x, t = threadIdx.x;
    int g = b >= NCHUNK ? 1 : 0;
    int bb = b - g * NCHUNK;
    int* dp = data + g * GN;
    int base = bb * 2048 + t * 4;
    int v0 = base + 0 < GN ? dp[base + 0] : 0;
    int v1 = base + 1 < GN ? dp[base + 1] : 0;
    int v2 = base + 2 < GN ? dp[base + 2] : 0;
    int v3 = base + 3 < GN ? dp[base + 3] : 0;
    int s = v0 + v1 + v2 + v3;
    ls[t] = s;
    __syncthreads();
    for (int off = 1; off < 512; off <<= 1) {
        int x = (t >= off) ? ls[t - off] : 0;
        __syncthreads();
        ls[t] += x;
        __syncthreads();
    }
    int excl = ls[t] - s;
    if (t == 511) csum[g * 128 + bb] = ls[511];
    if (base + 0 < GN) dp[base + 0] = excl;
    if (base + 1 < GN) dp[base + 1] = excl + v0;
    if (base + 2 < GN) dp[base + 2] = excl + v0 + v1;
    if (base + 3 < GN) dp[base + 3] = excl + v0 + v1 + v2;
}

__global__ void scan2_kernel(int* __restrict__ csum) {
    __shared__ int ls[128];
    int t = threadIdx.x;
    int* cp = csum + blockIdx.x * 128;
    int v = (t < NCHUNK) ? cp[t] : 0;
    ls[t] = v;
    __syncthreads();
    for (int off = 1; off < 128; off <<= 1) {
        int x = (t >= off) ? ls[t - off] : 0;
        __syncthreads();
        ls[t] += x;
        __syncthreads();
    }
    if (t < NCHUNK) cp[t] = ls[t] - v;
}

__global__ void scan3_kernel(int* __restrict__ rowptr, int* __restrict__ cursor,
                             const int* __restrict__ csum) {
    int i = blockIdx.x * 256 + threadIdx.x;
    if (i >= 2 * GN) return;
    int g = i >= GN ? 1 : 0;
    int ii = i - g * GN;
    int v = rowptr[i] + csum[g * 128 + (ii >> 11)];
    rowptr[i] = v;
    cursor[i] = v;
}

__global__ void fill2_kernel(const int* __restrict__ src0, const int* __restrict__ dst0,
                             const int* __restrict__ src1, const int* __restrict__ dst1,
                             int* __restrict__ cursor, int* __restrict__ eidx) {
    int e = blockIdx.x * 256 + threadIdx.x;
    if (e >= 2 * GE) return;
    int g = e >= GE ? 1 : 0;
    int ee = e - g * GE;
    const int* s = g ? src1 : src0;
    const int* d = g ? dst1 : dst0;
    int p = atomicAdd(&cursor[g * GN + d[ee]], 1);
    eidx[g * GE + p] = s[ee];
}

// ---------------- message passing ----------------
__global__ void msg1_kernel(const float* __restrict__ x0, const float* __restrict__ x1,
                            const int* __restrict__ rowptr, const int* __restrict__ cursor,
                            const int* __restrict__ eidx, float* __restrict__ msg1) {
    int i = blockIdx.x * 256 + threadIdx.x;
    if (i >= 2 * GN) return;
    int g = i >= GN ? 1 : 0;
    int n = i - g * GN;
    const float* x = g ? x1 : x0;
    const int* ei = eidx + g * GE;
    int k = rowptr[i], k1 = cursor[i];
    float a0 = 0.f, a1 = 0.f;
    for (; k + 1 < k1; k += 2) {
        int sa = ei[k], sb = ei[k + 1];
        float2 va = *(const float2*)&x[sa * 2];
        float2 vb = *(const float2*)&x[sb * 2];
        a0 += va.x + vb.x;
        a1 += va.y + vb.y;
    }
    if (k < k1) {
        int sa = ei[k];
        float2 va = *(const float2*)&x[sa * 2];
        a0 += va.x;
        a1 += va.y;
    }
    msg1[i * 2] = a0;
    msg1[i * 2 + 1] = a1;
}

// wave per node: 64 lanes x 2 channels; reads split g1 (hi+lo), writes split sums
__global__ void msg2_csr_kernel(const __bf16* __restrict__ gmh, const __bf16* __restrict__ gml,
                                const int* __restrict__ rowptr, const int* __restrict__ cursor,
                                const int* __restrict__ eidx,
                                __bf16* __restrict__ gmho, __bf16* __restrict__ gmlo) {
    int wid = (blockIdx.x * 256 + threadIdx.x) >> 6;
    int lane = threadIdx.x & 63;
    if (wid >= GN) return;
    int k = rowptr[wid], k1 = cursor[wid];
    int co = lane * 2;
    float a0 = 0.f, a1 = 0.f;
    for (; k + 1 < k1; k += 2) {
        int sa = eidx[k], sb = eidx[k + 1];
        unsigned int ha = *(const unsigned int*)&gmh[(size_t)sa * 256 + co];
        unsigned int la = *(const unsigned int*)&gml[(size_t)sa * 256 + co];
        unsigned int hb = *(const unsigned int*)&gmh[(size_t)sb * 256 + co];
        unsigned int lb = *(const unsigned int*)&gml[(size_t)sb * 256 + co];
        a0 += (bfu2f(ha & 0xffffu) + bfu2f(la & 0xffffu)) +
              (bfu2f(hb & 0xffffu) + bfu2f(lb & 0xffffu));
        a1 += (bfu2f(ha >> 16) + bfu2f(la >> 16)) +
              (bfu2f(hb >> 16) + bfu2f(lb >> 16));
    }
    if (k < k1) {
        int sa = eidx[k];
        unsigned int ha = *(const unsigned int*)&gmh[(size_t)sa * 256 + co];
        unsigned int la = *(const unsigned int*)&gml[(size_t)sa * 256 + co];
        a0 += bfu2f(ha & 0xffffu) + bfu2f(la & 0xffffu);
        a1 += bfu2f(ha >> 16) + bfu2f(la >> 16);
    }
    __bf16 h0 = (__bf16)a0, h1 = (__bf16)a1;
    bf16x2 hv = {h0, h1};
    bf16x2 lv = {(__bf16)(a0 - (float)h0), (__bf16)(a1 - (float)h1)};
    *(bf16x2*)&gmho[(size_t)wid * 256 + 128 + co] = hv;
    *(bf16x2*)&gmlo[(size_t)wid * 256 + 128 + co] = lv;
}

// ---------------- conv layer 1: writes split g1 (row-major) ----------------
__global__ void conv1_kernel(const float* __restrict__ x, const float* __restrict__ msg1,
                             const float* __restrict__ W1r, const float* __restrict__ W1n,
                             const float* __restrict__ b1,
                             __bf16* __restrict__ gmh, __bf16* __restrict__ gml) {
    int idx = blockIdx.x * 256 + threadIdx.x;   // n*128 + c
    int n = idx >> 7, c = idx & 127;
    float x0 = x[n * 2], x1 = x[n * 2 + 1];
    float m0 = msg1[n * 2], m1 = msg1[n * 2 + 1];
    float v = b1[c];
    v = fmaf(x0, W1r[c * 2], v);
    v = fmaf(x1, W1r[c * 2 + 1], v);
    v = fmaf(m0, W1n[c * 2], v);
    v = fmaf(m1, W1n[c * 2 + 1], v);
    v = v >= 0.f ? v : 0.01f * v;
    __bf16 h = (__bf16)v;
    gmh[(size_t)n * 256 + c] = h;
    gml[(size_t)n * 256 + c] = (__bf16)(v - (float)h);
}

// ---------------- weight prep ----------------
__global__ void prep_wcat_split(const float* __restrict__ W2r, const float* __restrict__ W2n,
                                __bf16* __restrict__ hi, __bf16* __restrict__ lo) {
    int idx = blockIdx.x * 256 + threadIdx.x;
    int c = idx >> 8, k = idx & 255;
    float v = (k < 128) ? W2r[c * 128 + k] : W2n[c * 128 + (k - 128)];
    __bf16 h = (__bf16)v;
    hi[idx] = h;
    lo[idx] = (__bf16)(v - (float)h);
}

__global__ void prep_split(const float* __restrict__ W, __bf16* __restrict__ hi,
                           __bf16* __restrict__ lo, int n) {
    int i = blockIdx.x * 256 + threadIdx.x;
    if (i >= n) return;
    float v = W[i];
    __bf16 h = (__bf16)v;
    hi[i] = h;
    lo[i] = (__bf16)(v - (float)h);
}

// ---------------- conv2 GEMM v5: SINGLE-buffer LDS (40KB) -> 4 blocks/CU ----------------
// C = lrelu([A] @ Wcat^T + b2). A split bf16 row-major [M][256], W split row-major [256][256].
// BM=64, BN=256 (4 waves x 64 cols), BK=32, K=256 fixed.
// LDS rows are 128B: slots 0..3 = hi kg0..3, 4..7 = lo kg0..3; slot' = slot ^ (row&7).
// MODE 1: RLE + atomicAdd(&out[aux[m]*ldo + n]) (aux = sorted batch)
// MODE 2: A-row indirect via aux/aux2; write use-style at col offset 256/512
template <int MODE>
__global__ __launch_bounds__(256, 4)
void conv2_gemm(const __bf16* __restrict__ Agh, const __bf16* __restrict__ Agl,
                const __bf16* __restrict__ whi, const __bf16* __restrict__ wlo,
                const float* __restrict__ bias,
                float* __restrict__ out, int ldo, int M,
                const int* __restrict__ aux, const int* __restrict__ aux2) {
    __shared__ __attribute__((aligned(16))) __bf16 A1[64 * 64];
    __shared__ __attribute__((aligned(16))) __bf16 B1[256 * 64];
    const int tid = threadIdx.x, lane = tid & 63, wv = tid >> 6;
    const int fr = lane & 15, kq = lane >> 4;
    const int bm = blockIdx.x * 64;

    // ---- hoisted staging sources (per-lane) ----
    const __bf16* asrc[2]; int adst[2];
#pragma unroll
    for (int j = 0; j < 2; ++j) {
        int a = wv * 2 + j;
        int row = a * 8 + (lane >> 3);
        int slot = (lane & 7) ^ (row & 7);
        int m = bm + row;
        long r;
        if (MODE == 2) r = (m < M) ? (long)(m < GB ? aux[m] : aux2[m - GB]) : 0;
        else           r = m;
        asrc[j] = (slot < 4 ? Agh : Agl) + r * 256 + (slot & 3) * 8;
        adst[j] = a * 512;
    }
    const __bf16* bsrc[8]; int bdst[8];
#pragma unroll
    for (int j = 0; j < 8; ++j) {
        int bc = wv * 8 + j;
        int col = bc * 8 + (lane >> 3);
        int slot = (lane & 7) ^ (col & 7);
        bsrc[j] = (slot < 4 ? whi : wlo) + (size_t)col * 256 + (slot & 3) * 8;
        bdst[j] = bc * 512;
    }
    // ---- fragment LDS offsets (swizzled reads) ----
    int aoh[4], aol[4], boh[4], bol[4];
#pragma unroll
    for (int mt = 0; mt < 4; ++mt) {
        int row = mt * 16 + fr;
        aoh[mt] = row * 64 + ((kq       ^ (row & 7)) * 8);
        aol[mt] = row * 64 + (((kq | 4) ^ (row & 7)) * 8);
    }
#pragma unroll
    for (int nt = 0; nt < 4; ++nt) {
        int col = wv * 64 + nt * 16 + fr;
        boh[nt] = col * 64 + ((kq       ^ (col & 7)) * 8);
        bol[nt] = col * 64 + (((kq | 4) ^ (col & 7)) * 8);
    }

    f32x4 acc[4][4];
#pragma unroll
    for (int i = 0; i < 4; ++i)
#pragma unroll
        for (int j = 0; j < 4; ++j) acc[i][j] = (f32x4){0.f, 0.f, 0.f, 0.f};

#pragma unroll
    for (int t = 0; t < 8; ++t) {
        int ks = t * 32;
#pragma unroll
        for (int j = 0; j < 2; ++j) g2l16(asrc[j] + ks, &A1[adst[j]]);
#pragma unroll
        for (int j = 0; j < 8; ++j) g2l16(bsrc[j] + ks, &B1[bdst[j]]);
        __syncthreads();   // drains vmcnt(0): staged data visible

        bf16x8 ah[4], al[4], bh[4], bl[4];
#pragma unroll
        for (int mt = 0; mt < 4; ++mt) {
            ah[mt] = *(const bf16x8*)&A1[aoh[mt]];
            al[mt] = *(const bf16x8*)&A1[aol[mt]];
        }
#pragma unroll
        for (int nt = 0; nt < 4; ++nt) {
            bh[nt] = *(const bf16x8*)&B1[boh[nt]];
            bl[nt] = *(const bf16x8*)&B1[bol[nt]];
        }
#pragma unroll
        for (int mt = 0; mt < 4; ++mt)
#pragma unroll
            for (int nt = 0; nt < 4; ++nt) {
                acc[mt][nt] = __builtin_amdgcn_mfma_f32_16x16x32_bf16(ah[mt], bh[nt], acc[mt][nt], 0, 0, 0);
                acc[mt][nt] = __builtin_amdgcn_mfma_f32_16x16x32_bf16(ah[mt], bl[nt], acc[mt][nt], 0, 0, 0);
                acc[mt][nt] = __builtin_amdgcn_mfma_f32_16x16x32_bf16(al[mt], bh[nt], acc[mt][nt], 0, 0, 0);
            }
        __syncthreads();   // frag reads done before next stage overwrites
    }

    // ---- epilogue ----
    const int q4 = kq * 4;
    const int cb = wv * 64;

    if (MODE == 1) {
        float s0 = 0.f, s1 = 0.f, s2 = 0.f, s3 = 0.f;
        int cur2 = -1;
        float bi0 = bias[cb + 0 * 16 + fr], bi1 = bias[cb + 1 * 16 + fr];
        float bi2 = bias[cb + 2 * 16 + fr], bi3 = bias[cb + 3 * 16 + fr];
#pragma unroll
        for (int mt = 0; mt < 4; ++mt) {
#pragma unroll
            for (int j = 0; j < 4; ++j) {
                int m = bm + mt * 16 + q4 + j;
                if (m < M) {
                    float v0 = acc[mt][0][j] + bi0;
                    float v1 = acc[mt][1][j] + bi1;
                    float v2 = acc[mt][2][j] + bi2;
                    float v3 = acc[mt][3][j] + bi3;
                    v0 = v0 >= 0.f ? v0 : 0.01f * v0;
                    v1 = v1 >= 0.f ? v1 : 0.01f * v1;
                    v2 = v2 >= 0.f ? v2 : 0.01f * v2;
                    v3 = v3 >= 0.f ? v3 : 0.01f * v3;
                    int b = aux[m];
                    if (b != cur2) {
                        if (cur2 >= 0) {
                            atomicAdd(&out[(size_t)cur2 * ldo + cb + 0 * 16 + fr], s0);
                            atomicAdd(&out[(size_t)cur2 * ldo + cb + 1 * 16 + fr], s1);
                            atomicAdd(&out[(size_t)cur2 * ldo + cb + 2 * 16 + fr], s2);
                            atomicAdd(&out[(size_t)cur2 * ldo + cb + 3 * 16 + fr], s3);
                        }
                        cur2 = b; s0 = v0; s1 = v1; s2 = v2; s3 = v3;
                    } else {
                        s0 += v0; s1 += v1; s2 += v2; s3 += v3;
                    }
                }
            }
        }
        if (cur2 >= 0) {
            atomicAdd(&out[(size_t)cur2 * ldo + cb + 0 * 16 + fr], s0);
            atomicAdd(&out[(size_t)cur2 * ldo + cb + 1 * 16 + fr], s1);
            atomicAdd(&out[(size_t)cur2 * ldo + cb + 2 * 16 + fr], s2);
            atomicAdd(&out[(size_t)cur2 * ldo + cb + 3 * 16 + fr], s3);
        }
    } else {
#pragma unroll
        for (int mt = 0; mt < 4; ++mt) {
#pragma unroll
            for (int j = 0; j < 4; ++j) {
                int m = bm + mt * 16 + q4 + j;
                if (m >= M) continue;
                int orow = (m < GB) ? m : m - GB;
                int ocol = (m < GB) ? 256 : 512;
                size_t obase = (size_t)orow * ldo + ocol;
#pragma unroll
                for (int nt = 0; nt < 4; ++nt) {
                    int cc = cb + nt * 16 + fr;
                    float v = acc[mt][nt][j] + bias[cc];
                    v = v >= 0.f ? v : 0.01f * v;
                    out[obase + cc] = v;
                }
            }
        }
    }
}

// ---------------- small-M MFMA GEMM for MLPs (LDS-A + direct-B) ----------------
template <int ACT, int PRESPLIT, int OSPLIT>
__global__ __launch_bounds__(256, 3)
void mfma_gemm2(const float* __restrict__ Af,
                const __bf16* __restrict__ Agh, const __bf16* __restrict__ Agl, int lda,
                const __bf16* __restrict__ whi, const __bf16* __restrict__ wlo,
                const float* __restrict__ bias,
                float* __restrict__ out, __bf16* __restrict__ outh, __bf16* __restrict__ outl,
                int ldo, int M, int K, int ctiles) {
    __shared__ __bf16 Ah[64][40], Al[64][40];
    const int bm = (blockIdx.x / ctiles) * 64;
    const int bn = (blockIdx.x % ctiles) * 256;
    const int tid = threadIdx.x, lane = tid & 63, wv = tid >> 6;

    const int sar = tid >> 2;
    const int sak = (tid & 3) * 8;
    const int arow = bm + sar;
    long asrc = arow < M ? arow : M - 1;
    const float*  Arf = PRESPLIT ? nullptr : (Af + (size_t)asrc * lda);
    const __bf16* Arh = PRESPLIT ? (Agh + (size_t)asrc * lda) : nullptr;
    const __bf16* Arl = PRESPLIT ? (Agl + (size_t)asrc * lda) : nullptr;

    const int fr = lane & 15, kg = (lane >> 4) * 8;
    const int cb = bn + wv * 64;

    const __bf16* bph[4];
    const __bf16* bpl[4];
#pragma unroll
    for (int nt = 0; nt < 4; ++nt) {
        bph[nt] = whi + (size_t)(cb + nt * 16 + fr) * K + kg;
        bpl[nt] = wlo + (size_t)(cb + nt * 16 + fr) * K + kg;
    }

    f32x4 acc[4][4];
#pragma unroll
    for (int i = 0; i < 4; ++i)
#pragma unroll
        for (int j = 0; j < 4; ++j) acc[i][j] = (f32x4){0.f, 0.f, 0.f, 0.f};

    for (int ks = 0; ks < K; ks += 32) {
        uint4 hv, lv;
        if (PRESPLIT) {
            hv = *(const uint4*)(Arh + ks + sak);
            lv = *(const uint4*)(Arl + ks + sak);
        } else {
            float4 a0 = *(const float4*)(Arf + ks + sak);
            float4 a1 = *(const float4*)(Arf + ks + sak + 4);
            float va[8] = {a0.x, a0.y, a0.z, a0.w, a1.x, a1.y, a1.z, a1.w};
            bf16x8 h8, l8;
#pragma unroll
            for (int e = 0; e < 8; ++e) {
                float v = va[e];
                __bf16 h = (__bf16)v;
                h8[e] = h;
                l8[e] = (__bf16)(v - (float)h);
            }
            hv = *(uint4*)&h8;
            lv = *(uint4*)&l8;
        }
        __syncthreads();
        *(uint4*)&Ah[sar][sak] = hv;
        *(uint4*)&Al[sar][sak] = lv;
        __syncthreads();

        bf16x8 ah[4], al[4], bh[4], bl[4];
#pragma unroll
        for (int nt = 0; nt < 4; ++nt) {
            bh[nt] = *(const bf16x8*)(bph[nt] + ks);
            bl[nt] = *(const bf16x8*)(bpl[nt] + ks);
        }
#pragma unroll
        for (int mt = 0; mt < 4; ++mt) {
            ah[mt] = *(const bf16x8*)&Ah[mt * 16 + fr][kg];
            al[mt] = *(const bf16x8*)&Al[mt * 16 + fr][kg];
        }
#pragma unroll
        for (int mt = 0; mt < 4; ++mt)
#pragma unroll
            for (int nt = 0; nt < 4; ++nt) {
                acc[mt][nt] = __builtin_amdgcn_mfma_f32_16x16x32_bf16(ah[mt], bh[nt], acc[mt][nt], 0, 0, 0);
                acc[mt][nt] = __builtin_amdgcn_mfma_f32_16x16x32_bf16(ah[mt], bl[nt], acc[mt][nt], 0, 0, 0);
                acc[mt][nt] = __builtin_amdgcn_mfma_f32_16x16x32_bf16(al[mt], bh[nt], acc[mt][nt], 0, 0, 0);
            }
    }

    const int q4 = (lane >> 4) * 4;
#pragma unroll
    for (int mt = 0; mt < 4; ++mt) {
#pragma unroll
        for (int j = 0; j < 4; ++j) {
            int m = bm + mt * 16 + q4 + j;
            if (m >= M) continue;
            size_t obase = (size_t)m * ldo;
#pragma unroll
            for (int nt = 0; nt < 4; ++nt) {
                int cc = cb + nt * 16 + fr;
                float v = acc[mt][nt][j] + bias[cc];
                if (ACT == 1) v = v >= 0.f ? v : 0.01f * v;
                if (ACT == 2) v = tanhf(v);
                if (OSPLIT) {
                    __bf16 h = (__bf16)v;
                    outh[obase + cc] = h;
                    outl[obase + cc] = (__bf16)(v - (float)h);
                } else {
                    out[obase + cc] = v;
                }
            }
        }
    }
}

// ---------------- output head ----------------
__global__ void outhead_kernel(const float* __restrict__ h, const float* __restrict__ W,
                               const float* __restrict__ bias, float* __restrict__ yp, int nout) {
    int idx = blockIdx.x * 256 + threadIdx.x;
    if (idx >= GB * nout) return;
    int b = idx / nout, o = idx - b * nout;
    const float4* hr = (const float4*)(h + (size_t)b * 512);
    const float4* wr = (const float4*)(W + (size_t)o * 512);
    float s = 0.f;
#pragma unroll 4
    for (int k = 0; k < 128; ++k) {
        float4 hv = hr[k], wv = wr[k];
        s = fmaf(hv.x, wv.x, s);
        s = fmaf(hv.y, wv.y, s);
        s = fmaf(hv.z, wv.z, s);
        s = fmaf(hv.w, wv.w, s);
    }
    yp[b * nout + o] = s + bias[o];
}

// ---------------- losses ----------------
__global__ void loss_kernel(const float* __restrict__ ypx, const float* __restrict__ ypA,
                            const float* __restrict__ y_x, const float* __restrict__ y_A,
                            float* __restrict__ out) {
    int b = blockIdx.x * 256 + threadIdx.x;
    if (b >= GB) return;
#pragma unroll
    for (int j = 0; j < 2; ++j) {
        float p  = ypx[b * 4 + j];
        float a  = p * p + 1e-7f;
        float mu = ypx[b * 4 + 2 + j];
        float e  = (y_x[b * 2 + j] - mu) / a;
        out[b * 2 + j] = e * e + logf(a);
    }
    float p  = ypA[b * 2 + 0];
    float a  = p * p + 1e-7f;
    float mu = ypA[b * 2 + 1];
    float e  = (y_A[b] - mu) / a;
    out[2 * GB + b] = e * e + logf(a);
}

extern "C" void kernel_launch(void* const* d_in, const int* in_sizes, int n_in,
                              void* d_out, int out_size, void* d_ws, size_t ws_size,
                              hipStream_t stream) {
    const float* x_x     = (const float*)d_in[0];
    const float* y_x     = (const float*)d_in[1];
    const int*   ei_x    = (const int*)d_in[2];
    const int*   batch_x = (const int*)d_in[3];
    const float* x_A     = (const float*)d_in[4];
    const float* y_A     = (const float*)d_in[5];
    const int*   ei_A    = (const int*)d_in[6];
    const int*   batch_A = (const int*)d_in[7];
    const int*   idi_A   = (const int*)d_in[8];
    const int*   idj_A   = (const int*)d_in[9];
    const float* W1r = (const float*)d_in[10];
    const float* W1n = (const float*)d_in[11];
    const float* b1  = (const float*)d_in[12];
    const float* W2r = (const float*)d_in[13];
    const float* W2n = (const float*)d_in[14];
    const float* b2  = (const float*)d_in[15];
    const float* nW1 = (const float*)d_in[16];
    const float* nb1 = (const float*)d_in[17];
    const float* nW2 = (const float*)d_in[18];
    const float* nb2 = (const float*)d_in[19];
    const float* nW3 = (const float*)d_in[20];
    const float* nb3 = (const float*)d_in[21];
    const float* eW1 = (const float*)d_in[22];
    const float* eb1 = (const float*)d_in[23];
    const float* eW2 = (const float*)d_in[24];
    const float* eb2 = (const float*)d_in[25];
    const float* eW3 = (const float*)d_in[26];
    const float* eb3 = (const float*)d_in[27];

    // ---- workspace layout ----
    __bf16* gmh  = (__bf16*)d_ws;                    // GN*256
    __bf16* gml  = gmh + (size_t)GN * 256;           // GN*256
    float*  msg1 = (float*)(gml + (size_t)GN * 256); // 2*GN*2
    float*  rgx  = msg1 + (size_t)2 * GN * 2;        // GB*256
    float*  use  = rgx  + (size_t)GB * 256;          // GB*768
    __bf16* wcat_hi = (__bf16*)(use + (size_t)GB * 768);
    __bf16* wcat_lo = wcat_hi + 65536;
    __bf16* nW1hi = wcat_lo + 65536;
    __bf16* nW1lo = nW1hi + 65536;
    __bf16* nW2hi = nW1lo + 65536;
    __bf16* nW2lo = nW2hi + 131072;
    __bf16* eW1hi = nW2lo + 131072;
    __bf16* eW1lo = eW1hi + 196608;
    __bf16* eW2hi = eW1lo + 196608;
    __bf16* eW2lo = eW2hi + 131072;
    int* rowptr = (int*)(eW2lo + 131072);            // 2*GN
    int* cursor = rowptr + 2 * GN;                   // 2*GN
    int* eidx   = cursor + 2 * GN;                   // 2*GE
    int* csum   = eidx + 2 * GE;                     // 256
    char* wend  = (char*)(csum + 256);
    // aliases into gmh/gml region (dead after sel-GEMM):
    __bf16* h1h = gmh;
    __bf16* h1l = h1h + (size_t)GB * 256;
    float*  h2  = (float*)(h1l + (size_t)GB * 256);
    float*  ypx = h2 + (size_t)GB * 512;
    float*  ypA = ypx + (size_t)GB * 4;

    size_t need = (size_t)(wend - (char*)d_ws);
    if (ws_size < need) return;

    float* out = (float*)d_out;

    // weight prep
    prep_wcat_split<<<256, 256, 0, stream>>>(W2r, W2n, wcat_hi, wcat_lo);
    prep_split<<<256, 256, 0, stream>>>(nW1, nW1hi, nW1lo, 65536);
    prep_split<<<512, 256, 0, stream>>>(nW2, nW2hi, nW2lo, 131072);
    prep_split<<<768, 256, 0, stream>>>(eW1, eW1hi, eW1lo, 196608);
    prep_split<<<512, 256, 0, stream>>>(eW2, eW2hi, eW2lo, 131072);

    // CSR + msg1 for BOTH graphs, fused
    hipMemsetAsync(rowptr, 0, (size_t)2 * GN * sizeof(int), stream);
    deg2_kernel<<<(2 * GE + 255) / 256, 256, 0, stream>>>(ei_x + GE, ei_A + GE, rowptr);
    scan1_kernel<<<2 * NCHUNK, 512, 0, stream>>>(rowptr, csum);
    scan2_kernel<<<2, 128, 0, stream>>>(csum);
    scan3_kernel<<<(2 * GN + 255) / 256, 256, 0, stream>>>(rowptr, cursor, csum);
    fill2_kernel<<<(2 * GE + 255) / 256, 256, 0, stream>>>(ei_x, ei_x + GE, ei_A, ei_A + GE,
                                                           cursor, eidx);
    msg1_kernel<<<(2 * GN + 255) / 256, 256, 0, stream>>>(x_x, x_A, rowptr, cursor, eidx, msg1);

    const int conv2_grid = GN / 64;                 // 3125
    const int sel_grid   = (2 * GB + 63) / 64;      // 313
    const int mlp_mt     = (GB + 63) / 64;          // 157

    for (int g = 0; g < 2; ++g) {
        const float* x = g == 0 ? x_x : x_A;
        const int* rp  = rowptr + g * GN;
        const int* cu  = cursor + g * GN;
        const int* ei  = eidx + (size_t)g * GE;
        const int* bat = g == 0 ? batch_x : batch_A;

        conv1_kernel<<<GN * 128 / 256, 256, 0, stream>>>(x, msg1 + (size_t)g * GN * 2,
                                                         W1r, W1n, b1, gmh, gml);
        msg2_csr_kernel<<<GN / 4, 256, 0, stream>>>(gmh, gml, rp, cu, ei, gmh, gml);

        if (g == 0) {
            hipMemsetAsync(rgx, 0, (size_t)GB * 256 * sizeof(float), stream);
            conv2_gemm<1><<<conv2_grid, 256, 0, stream>>>(
                gmh, gml, wcat_hi, wcat_lo, b2, rgx, 256, GN, bat, nullptr);
        } else {
            hipMemsetAsync(use, 0, (size_t)GB * 768 * sizeof(float), stream);
            conv2_gemm<1><<<conv2_grid, 256, 0, stream>>>(
                gmh, gml, wcat_hi, wcat_lo, b2, use, 768, GN, bat, nullptr);
            conv2_gemm<2><<<sel_grid, 256, 0, stream>>>(
                gmh, gml, wcat_hi, wcat_lo, b2, use, 768, 2 * GB, idi_A, idj_A);
        }
    }

    // node MLP (h1/h2 alias gmh region; gm dead now)
    mfma_gemm2<2, 0, 1><<<mlp_mt, 256, 0, stream>>>(
        rgx, nullptr, nullptr, 256, nW1hi, nW1lo, nb1,
        nullptr, h1h, h1l, 256, GB, 256, 1);
    mfma_gemm2<2, 1, 0><<<mlp_mt * 2, 256, 0, stream>>>(
        nullptr, h1h, h1l, 256, nW2hi, nW2lo, nb2,
        h2, nullptr, nullptr, 512, GB, 256, 2);
    outhead_kernel<<<(GB * 4 + 255) / 256, 256, 0, stream>>>(h2, nW3, nb3, ypx, 4);

    // edge MLP
    mfma_gemm2<2, 0, 1><<<mlp_mt, 256, 0, stream>>>(
        use, nullptr, nullptr, 768, eW1hi, eW1lo, eb1,
        nullptr, h1h, h1l, 256, GB, 768, 1);
    mfma_gemm2<2, 1, 0><<<mlp_mt * 2, 256, 0, stream>>>(
        nullptr, h1h, h1l, 256, eW2hi, eW2lo, eb2,
        h2, nullptr, nullptr, 512, GB, 256, 2);
    outhead_kernel<<<(GB * 2 + 255) / 256, 256, 0, stream>>>(h2, eW3, eb3, ypA, 2);

    loss_kernel<<<(GB + 255) / 256, 256, 0, stream>>>(ypx, ypA, y_x, y_A, out);
}

// Round 9
// 937.439 us; speedup vs baseline: 1.1740x; 1.1740x over previous
//
#include <hip/hip_runtime.h>
#include <hip/hip_bf16.h>

#define GN 200000
#define GB 10000
#define GE 600000
#define NCHUNK 98   // ceil(GN/2048)

typedef __bf16 bf16x8 __attribute__((ext_vector_type(8)));
typedef __bf16 bf16x2 __attribute__((ext_vector_type(2)));
typedef float  f32x4  __attribute__((ext_vector_type(4)));

__device__ inline float bfu2f(unsigned int u) {
    union { unsigned int i; float f; } c;
    c.i = u << 16;
    return c.f;
}

// async global->LDS, 16B per lane; lds dest = uniform base + lane*16
__device__ __forceinline__ void g2l16(const void* g, void* l) {
    __builtin_amdgcn_global_load_lds(
        (const __attribute__((address_space(1))) unsigned int*)g,
        (__attribute__((address_space(3))) unsigned int*)l, 16, 0, 0);
}

// ---------------- CSR construction (both graphs fused) ----------------
__global__ void deg2_kernel(const int* __restrict__ dst0, const int* __restrict__ dst1,
                            int* __restrict__ deg) {
    int e = blockIdx.x * 256 + threadIdx.x;
    if (e >= 2 * GE) return;
    int g = e >= GE ? 1 : 0;
    int ee = e - g * GE;
    const int* d = g ? dst1 : dst0;
    atomicAdd(&deg[g * GN + d[ee]], 1);
}

__global__ void scan1_kernel(int* __restrict__ data, int* __restrict__ csum) {
    __shared__ int ls[512];
    int b = blockIdx.x, t = threadIdx.x;
    int g = b >= NCHUNK ? 1 : 0;
    int bb = b - g * NCHUNK;
    int* dp = data + g * GN;
    int base = bb * 2048 + t * 4;
    int v0 = base + 0 < GN ? dp[base + 0] : 0;
    int v1 = base + 1 < GN ? dp[base + 1] : 0;
    int v2 = base + 2 < GN ? dp[base + 2] : 0;
    int v3 = base + 3 < GN ? dp[base + 3] : 0;
    int s = v0 + v1 + v2 + v3;
    ls[t] = s;
    __syncthreads();
    for (int off = 1; off < 512; off <<= 1) {
        int x = (t >= off) ? ls[t - off] : 0;
        __syncthreads();
        ls[t] += x;
        __syncthreads();
    }
    int excl = ls[t] - s;
    if (t == 511) csum[g * 128 + bb] = ls[511];
    if (base + 0 < GN) dp[base + 0] = excl;
    if (base + 1 < GN) dp[base + 1] = excl + v0;
    if (base + 2 < GN) dp[base + 2] = excl + v0 + v1;
    if (base + 3 < GN) dp[base + 3] = excl + v0 + v1 + v2;
}

__global__ void scan2_kernel(int* __restrict__ csum) {
    __shared__ int ls[128];
    int t = threadIdx.x;
    int* cp = csum + blockIdx.x * 128;
    int v = (t < NCHUNK) ? cp[t] : 0;
    ls[t] = v;
    __syncthreads();
    for (int off = 1; off < 128; off <<= 1) {
        int x = (t >= off) ? ls[t - off] : 0;
        __syncthreads();
        ls[t] += x;
        __syncthreads();
    }
    if (t < NCHUNK) cp[t] = ls[t] - v;
}

__global__ void scan3_kernel(int* __restrict__ rowptr, int* __restrict__ cursor,
                             const int* __restrict__ csum) {
    int i = blockIdx.x * 256 + threadIdx.x;
    if (i >= 2 * GN) return;
    int g = i >= GN ? 1 : 0;
    int ii = i - g * GN;
    int v = rowptr[i] + csum[g * 128 + (ii >> 11)];
    rowptr[i] = v;
    cursor[i] = v;
}

__global__ void fill2_kernel(const int* __restrict__ src0, const int* __restrict__ dst0,
                             const int* __restrict__ src1, const int* __restrict__ dst1,
                             int* __restrict__ cursor, int* __restrict__ eidx) {
    int e = blockIdx.x * 256 + threadIdx.x;
    if (e >= 2 * GE) return;
    int g = e >= GE ? 1 : 0;
    int ee = e - g * GE;
    const int* s = g ? src1 : src0;
    const int* d = g ? dst1 : dst0;
    int p = atomicAdd(&cursor[g * GN + d[ee]], 1);
    eidx[g * GE + p] = s[ee];
}

// ---------------- message passing ----------------
__global__ void msg1_kernel(const float* __restrict__ x0, const float* __restrict__ x1,
                            const int* __restrict__ rowptr, const int* __restrict__ cursor,
                            const int* __restrict__ eidx, float* __restrict__ msg1) {
    int i = blockIdx.x * 256 + threadIdx.x;
    if (i >= 2 * GN) return;
    int g = i >= GN ? 1 : 0;
    int n = i - g * GN;
    const float* x = g ? x1 : x0;
    const int* ei = eidx + g * GE;
    int k = rowptr[i], k1 = cursor[i];
    float a0 = 0.f, a1 = 0.f;
    for (; k + 1 < k1; k += 2) {
        int sa = ei[k], sb = ei[k + 1];
        float2 va = *(const float2*)&x[sa * 2];
        float2 vb = *(const float2*)&x[sb * 2];
        a0 += va.x + vb.x;
        a1 += va.y + vb.y;
    }
    if (k < k1) {
        int sa = ei[k];
        float2 va = *(const float2*)&x[sa * 2];
        a0 += va.x;
        a1 += va.y;
    }
    msg1[i * 2] = a0;
    msg1[i * 2 + 1] = a1;
}

// wave per node: 64 lanes x 2 channels; reads split g1 (hi+lo), writes split sums
__global__ void msg2_csr_kernel(const __bf16* __restrict__ gmh, const __bf16* __restrict__ gml,
                                const int* __restrict__ rowptr, const int* __restrict__ cursor,
                                const int* __restrict__ eidx,
                                __bf16* __restrict__ gmho, __bf16* __restrict__ gmlo) {
    int wid = (blockIdx.x * 256 + threadIdx.x) >> 6;
    int lane = threadIdx.x & 63;
    if (wid >= GN) return;
    int k = rowptr[wid], k1 = cursor[wid];
    int co = lane * 2;
    float a0 = 0.f, a1 = 0.f;
    for (; k + 1 < k1; k += 2) {
        int sa = eidx[k], sb = eidx[k + 1];
        unsigned int ha = *(const unsigned int*)&gmh[(size_t)sa * 256 + co];
        unsigned int la = *(const unsigned int*)&gml[(size_t)sa * 256 + co];
        unsigned int hb = *(const unsigned int*)&gmh[(size_t)sb * 256 + co];
        unsigned int lb = *(const unsigned int*)&gml[(size_t)sb * 256 + co];
        a0 += (bfu2f(ha & 0xffffu) + bfu2f(la & 0xffffu)) +
              (bfu2f(hb & 0xffffu) + bfu2f(lb & 0xffffu));
        a1 += (bfu2f(ha >> 16) + bfu2f(la >> 16)) +
              (bfu2f(hb >> 16) + bfu2f(lb >> 16));
    }
    if (k < k1) {
        int sa = eidx[k];
        unsigned int ha = *(const unsigned int*)&gmh[(size_t)sa * 256 + co];
        unsigned int la = *(const unsigned int*)&gml[(size_t)sa * 256 + co];
        a0 += bfu2f(ha & 0xffffu) + bfu2f(la & 0xffffu);
        a1 += bfu2f(ha >> 16) + bfu2f(la >> 16);
    }
    __bf16 h0 = (__bf16)a0, h1 = (__bf16)a1;
    bf16x2 hv = {h0, h1};
    bf16x2 lv = {(__bf16)(a0 - (float)h0), (__bf16)(a1 - (float)h1)};
    *(bf16x2*)&gmho[(size_t)wid * 256 + 128 + co] = hv;
    *(bf16x2*)&gmlo[(size_t)wid * 256 + 128 + co] = lv;
}

// ---------------- conv layer 1: writes split g1 (row-major) ----------------
__global__ void conv1_kernel(const float* __restrict__ x, const float* __restrict__ msg1,
                             const float* __restrict__ W1r, const float* __restrict__ W1n,
                             const float* __restrict__ b1,
                             __bf16* __restrict__ gmh, __bf16* __restrict__ gml) {
    int idx = blockIdx.x * 256 + threadIdx.x;   // n*128 + c
    int n = idx >> 7, c = idx & 127;
    float x0 = x[n * 2], x1 = x[n * 2 + 1];
    float m0 = msg1[n * 2], m1 = msg1[n * 2 + 1];
    float v = b1[c];
    v = fmaf(x0, W1r[c * 2], v);
    v = fmaf(x1, W1r[c * 2 + 1], v);
    v = fmaf(m0, W1n[c * 2], v);
    v = fmaf(m1, W1n[c * 2 + 1], v);
    v = v >= 0.f ? v : 0.01f * v;
    __bf16 h = (__bf16)v;
    gmh[(size_t)n * 256 + c] = h;
    gml[(size_t)n * 256 + c] = (__bf16)(v - (float)h);
}

// ---------------- weight prep ----------------
__global__ void prep_wcat_split(const float* __restrict__ W2r, const float* __restrict__ W2n,
                                __bf16* __restrict__ hi, __bf16* __restrict__ lo) {
    int idx = blockIdx.x * 256 + threadIdx.x;
    int c = idx >> 8, k = idx & 255;
    float v = (k < 128) ? W2r[c * 128 + k] : W2n[c * 128 + (k - 128)];
    __bf16 h = (__bf16)v;
    hi[idx] = h;
    lo[idx] = (__bf16)(v - (float)h);
}

__global__ void prep_split(const float* __restrict__ W, __bf16* __restrict__ hi,
                           __bf16* __restrict__ lo, int n) {
    int i = blockIdx.x * 256 + threadIdx.x;
    if (i >= n) return;
    float v = W[i];
    __bf16 h = (__bf16)v;
    hi[i] = h;
    lo[i] = (__bf16)(v - (float)h);
}

// ---------------- conv2 GEMM v6: dbuf + COUNTED vmcnt pipeline (T3/T4) ----------------
// Same geometry/swizzle as round-7 kernel (verified): BM=64, BN=256, BK=32, K=256.
// LDS rows 128B: slots 0..3 = hi kg0..3, 4..7 = lo kg0..3; slot' = slot ^ (row&7).
// Pipeline: stage(t) waits via vmcnt(10) (10 g2l16/wave/stage); stage(t+2) issued after
// the read-done barrier so its latency is covered by the 48 MFMAs. Raw s_barrier (no
// implicit vmcnt(0) drain). t=7 drains vmcnt(0).
template <int MODE>
__global__ __launch_bounds__(256, 2)
void conv2_gemm(const __bf16* __restrict__ Agh, const __bf16* __restrict__ Agl,
                const __bf16* __restrict__ whi, const __bf16* __restrict__ wlo,
                const float* __restrict__ bias,
                float* __restrict__ out, int ldo, int M,
                const int* __restrict__ aux, const int* __restrict__ aux2) {
    __shared__ __attribute__((aligned(16))) __bf16 A2[2][64 * 64];
    __shared__ __attribute__((aligned(16))) __bf16 B2[2][256 * 64];
    const int tid = threadIdx.x, lane = tid & 63, wv = tid >> 6;
    const int fr = lane & 15, kq = lane >> 4;
    const int bm = blockIdx.x * 64;

    // ---- hoisted staging sources (per-lane) ----
    const __bf16* asrc[2]; int adst[2];
#pragma unroll
    for (int j = 0; j < 2; ++j) {
        int a = wv * 2 + j;
        int row = a * 8 + (lane >> 3);
        int slot = (lane & 7) ^ (row & 7);
        int m = bm + row;
        long r;
        if (MODE == 2) r = (m < M) ? (long)(m < GB ? aux[m] : aux2[m - GB]) : 0;
        else           r = m;
        asrc[j] = (slot < 4 ? Agh : Agl) + r * 256 + (slot & 3) * 8;
        adst[j] = a * 512;
    }
    const __bf16* bsrc[8]; int bdst[8];
#pragma unroll
    for (int j = 0; j < 8; ++j) {
        int bc = wv * 8 + j;
        int col = bc * 8 + (lane >> 3);
        int slot = (lane & 7) ^ (col & 7);
        bsrc[j] = (slot < 4 ? whi : wlo) + (size_t)col * 256 + (slot & 3) * 8;
        bdst[j] = bc * 512;
    }
    // ---- fragment LDS offsets (swizzled reads) ----
    int aoh[4], aol[4], boh[4], bol[4];
#pragma unroll
    for (int mt = 0; mt < 4; ++mt) {
        int row = mt * 16 + fr;
        aoh[mt] = row * 64 + ((kq       ^ (row & 7)) * 8);
        aol[mt] = row * 64 + (((kq | 4) ^ (row & 7)) * 8);
    }
#pragma unroll
    for (int nt = 0; nt < 4; ++nt) {
        int col = wv * 64 + nt * 16 + fr;
        boh[nt] = col * 64 + ((kq       ^ (col & 7)) * 8);
        bol[nt] = col * 64 + (((kq | 4) ^ (col & 7)) * 8);
    }

    f32x4 acc[4][4];
#pragma unroll
    for (int i = 0; i < 4; ++i)
#pragma unroll
        for (int j = 0; j < 4; ++j) acc[i][j] = (f32x4){0.f, 0.f, 0.f, 0.f};

    // prologue: stage 0 -> buf0, stage 1 -> buf1 (20 loads/wave outstanding)
#pragma unroll
    for (int j = 0; j < 2; ++j) g2l16(asrc[j], &A2[0][adst[j]]);
#pragma unroll
    for (int j = 0; j < 8; ++j) g2l16(bsrc[j], &B2[0][bdst[j]]);
#pragma unroll
    for (int j = 0; j < 2; ++j) g2l16(asrc[j] + 32, &A2[1][adst[j]]);
#pragma unroll
    for (int j = 0; j < 8; ++j) g2l16(bsrc[j] + 32, &B2[1][bdst[j]]);

#pragma unroll
    for (int t = 0; t < 8; ++t) {
        const int cur = t & 1;
        // wait for stage(t): 10 loads/stage; stage(t+1) (and nothing else) may remain
        if (t < 7) asm volatile("s_waitcnt vmcnt(10)" ::: "memory");
        else       asm volatile("s_waitcnt vmcnt(0)" ::: "memory");
        __builtin_amdgcn_s_barrier();          // all waves' stage(t) visible

        bf16x8 ah[4], al[4], bh[4], bl[4];
#pragma unroll
        for (int mt = 0; mt < 4; ++mt) {
            ah[mt] = *(const bf16x8*)&A2[cur][aoh[mt]];
            al[mt] = *(const bf16x8*)&A2[cur][aol[mt]];
        }
#pragma unroll
        for (int nt = 0; nt < 4; ++nt) {
            bh[nt] = *(const bf16x8*)&B2[cur][boh[nt]];
            bl[nt] = *(const bf16x8*)&B2[cur][bol[nt]];
        }
        asm volatile("s_waitcnt lgkmcnt(0)" ::: "memory");
        __builtin_amdgcn_sched_barrier(0);     // rule #18: pin MFMA below the wait
        __builtin_amdgcn_s_barrier();          // all waves done reading buf[cur]

        if (t + 2 < 8) {                       // refill buf[cur] with stage(t+2)
            int ks = (t + 2) * 32;
#pragma unroll
            for (int j = 0; j < 2; ++j) g2l16(asrc[j] + ks, &A2[cur][adst[j]]);
#pragma unroll
            for (int j = 0; j < 8; ++j) g2l16(bsrc[j] + ks, &B2[cur][bdst[j]]);
        }
#pragma unroll
        for (int mt = 0; mt < 4; ++mt)
#pragma unroll
            for (int nt = 0; nt < 4; ++nt) {
                acc[mt][nt] = __builtin_amdgcn_mfma_f32_16x16x32_bf16(ah[mt], bh[nt], acc[mt][nt], 0, 0, 0);
                acc[mt][nt] = __builtin_amdgcn_mfma_f32_16x16x32_bf16(ah[mt], bl[nt], acc[mt][nt], 0, 0, 0);
                acc[mt][nt] = __builtin_amdgcn_mfma_f32_16x16x32_bf16(al[mt], bh[nt], acc[mt][nt], 0, 0, 0);
            }
    }

    // ---- epilogue (unchanged from round 7) ----
    const int q4 = kq * 4;
    const int cb = wv * 64;

    if (MODE == 1) {
        float s0 = 0.f, s1 = 0.f, s2 = 0.f, s3 = 0.f;
        int cur2 = -1;
        float bi0 = bias[cb + 0 * 16 + fr], bi1 = bias[cb + 1 * 16 + fr];
        float bi2 = bias[cb + 2 * 16 + fr], bi3 = bias[cb + 3 * 16 + fr];
#pragma unroll
        for (int mt = 0; mt < 4; ++mt) {
#pragma unroll
            for (int j = 0; j < 4; ++j) {
                int m = bm + mt * 16 + q4 + j;
                if (m < M) {
                    float v0 = acc[mt][0][j] + bi0;
                    float v1 = acc[mt][1][j] + bi1;
                    float v2 = acc[mt][2][j] + bi2;
                    float v3 = acc[mt][3][j] + bi3;
                    v0 = v0 >= 0.f ? v0 : 0.01f * v0;
                    v1 = v1 >= 0.f ? v1 : 0.01f * v1;
                    v2 = v2 >= 0.f ? v2 : 0.01f * v2;
                    v3 = v3 >= 0.f ? v3 : 0.01f * v3;
                    int b = aux[m];
                    if (b != cur2) {
                        if (cur2 >= 0) {
                            atomicAdd(&out[(size_t)cur2 * ldo + cb + 0 * 16 + fr], s0);
                            atomicAdd(&out[(size_t)cur2 * ldo + cb + 1 * 16 + fr], s1);
                            atomicAdd(&out[(size_t)cur2 * ldo + cb + 2 * 16 + fr], s2);
                            atomicAdd(&out[(size_t)cur2 * ldo + cb + 3 * 16 + fr], s3);
                        }
                        cur2 = b; s0 = v0; s1 = v1; s2 = v2; s3 = v3;
                    } else {
                        s0 += v0; s1 += v1; s2 += v2; s3 += v3;
                    }
                }
            }
        }
        if (cur2 >= 0) {
            atomicAdd(&out[(size_t)cur2 * ldo + cb + 0 * 16 + fr], s0);
            atomicAdd(&out[(size_t)cur2 * ldo + cb + 1 * 16 + fr], s1);
            atomicAdd(&out[(size_t)cur2 * ldo + cb + 2 * 16 + fr], s2);
            atomicAdd(&out[(size_t)cur2 * ldo + cb + 3 * 16 + fr], s3);
        }
    } else {
#pragma unroll
        for (int mt = 0; mt < 4; ++mt) {
#pragma unroll
            for (int j = 0; j < 4; ++j) {
                int m = bm + mt * 16 + q4 + j;
                if (m >= M) continue;
                int orow = (m < GB) ? m : m - GB;
                int ocol = (m < GB) ? 256 : 512;
                size_t obase = (size_t)orow * ldo + ocol;
#pragma unroll
                for (int nt = 0; nt < 4; ++nt) {
                    int cc = cb + nt * 16 + fr;
                    float v = acc[mt][nt][j] + bias[cc];
                    v = v >= 0.f ? v : 0.01f * v;
                    out[obase + cc] = v;
                }
            }
        }
    }
}

// ---------------- small-M MFMA GEMM for MLPs (LDS-A + direct-B) ----------------
template <int ACT, int PRESPLIT, int OSPLIT>
__global__ __launch_bounds__(256, 3)
void mfma_gemm2(const float* __restrict__ Af,
                const __bf16* __restrict__ Agh, const __bf16* __restrict__ Agl, int lda,
                const __bf16* __restrict__ whi, const __bf16* __restrict__ wlo,
                const float* __restrict__ bias,
                float* __restrict__ out, __bf16* __restrict__ outh, __bf16* __restrict__ outl,
                int ldo, int M, int K, int ctiles) {
    __shared__ __bf16 Ah[64][40], Al[64][40];
    const int bm = (blockIdx.x / ctiles) * 64;
    const int bn = (blockIdx.x % ctiles) * 256;
    const int tid = threadIdx.x, lane = tid & 63, wv = tid >> 6;

    const int sar = tid >> 2;
    const int sak = (tid & 3) * 8;
    const int arow = bm + sar;
    long asrc = arow < M ? arow : M - 1;
    const float*  Arf = PRESPLIT ? nullptr : (Af + (size_t)asrc * lda);
    const __bf16* Arh = PRESPLIT ? (Agh + (size_t)asrc * lda) : nullptr;
    const __bf16* Arl = PRESPLIT ? (Agl + (size_t)asrc * lda) : nullptr;

    const int fr = lane & 15, kg = (lane >> 4) * 8;
    const int cb = bn + wv * 64;

    const __bf16* bph[4];
    const __bf16* bpl[4];
#pragma unroll
    for (int nt = 0; nt < 4; ++nt) {
        bph[nt] = whi + (size_t)(cb + nt * 16 + fr) * K + kg;
        bpl[nt] = wlo + (size_t)(cb + nt * 16 + fr) * K + kg;
    }

    f32x4 acc[4][4];
#pragma unroll
    for (int i = 0; i < 4; ++i)
#pragma unroll
        for (int j = 0; j < 4; ++j) acc[i][j] = (f32x4){0.f, 0.f, 0.f, 0.f};

    for (int ks = 0; ks < K; ks += 32) {
        uint4 hv, lv;
        if (PRESPLIT) {
            hv = *(const uint4*)(Arh + ks + sak);
            lv = *(const uint4*)(Arl + ks + sak);
        } else {
            float4 a0 = *(const float4*)(Arf + ks + sak);
            float4 a1 = *(const float4*)(Arf + ks + sak + 4);
            float va[8] = {a0.x, a0.y, a0.z, a0.w, a1.x, a1.y, a1.z, a1.w};
            bf16x8 h8, l8;
#pragma unroll
            for (int e = 0; e < 8; ++e) {
                float v = va[e];
                __bf16 h = (__bf16)v;
                h8[e] = h;
                l8[e] = (__bf16)(v - (float)h);
            }
            hv = *(uint4*)&h8;
            lv = *(uint4*)&l8;
        }
        __syncthreads();
        *(uint4*)&Ah[sar][sak] = hv;
        *(uint4*)&Al[sar][sak] = lv;
        __syncthreads();

        bf16x8 ah[4], al[4], bh[4], bl[4];
#pragma unroll
        for (int nt = 0; nt < 4; ++nt) {
            bh[nt] = *(const bf16x8*)(bph[nt] + ks);
            bl[nt] = *(const bf16x8*)(bpl[nt] + ks);
        }
#pragma unroll
        for (int mt = 0; mt < 4; ++mt) {
            ah[mt] = *(const bf16x8*)&Ah[mt * 16 + fr][kg];
            al[mt] = *(const bf16x8*)&Al[mt * 16 + fr][kg];
        }
#pragma unroll
        for (int mt = 0; mt < 4; ++mt)
#pragma unroll
            for (int nt = 0; nt < 4; ++nt) {
                acc[mt][nt] = __builtin_amdgcn_mfma_f32_16x16x32_bf16(ah[mt], bh[nt], acc[mt][nt], 0, 0, 0);
                acc[mt][nt] = __builtin_amdgcn_mfma_f32_16x16x32_bf16(ah[mt], bl[nt], acc[mt][nt], 0, 0, 0);
                acc[mt][nt] = __builtin_amdgcn_mfma_f32_16x16x32_bf16(al[mt], bh[nt], acc[mt][nt], 0, 0, 0);
            }
    }

    const int q4 = (lane >> 4) * 4;
#pragma unroll
    for (int mt = 0; mt < 4; ++mt) {
#pragma unroll
        for (int j = 0; j < 4; ++j) {
            int m = bm + mt * 16 + q4 + j;
            if (m >= M) continue;
            size_t obase = (size_t)m * ldo;
#pragma unroll
            for (int nt = 0; nt < 4; ++nt) {
                int cc = cb + nt * 16 + fr;
                float v = acc[mt][nt][j] + bias[cc];
                if (ACT == 1) v = v >= 0.f ? v : 0.01f * v;
                if (ACT == 2) v = tanhf(v);
                if (OSPLIT) {
                    __bf16 h = (__bf16)v;
                    outh[obase + cc] = h;
                    outl[obase + cc] = (__bf16)(v - (float)h);
                } else {
                    out[obase + cc] = v;
                }
            }
        }
    }
}

// ---------------- output head ----------------
__global__ void outhead_kernel(const float* __restrict__ h, const float* __restrict__ W,
                               const float* __restrict__ bias, float* __restrict__ yp, int nout) {
    int idx = blockIdx.x * 256 + threadIdx.x;
    if (idx >= GB * nout) return;
    int b = idx / nout, o = idx - b * nout;
    const float4* hr = (const float4*)(h + (size_t)b * 512);
    const float4* wr = (const float4*)(W + (size_t)o * 512);
    float s = 0.f;
#pragma unroll 4
    for (int k = 0; k < 128; ++k) {
        float4 hv = hr[k], wv = wr[k];
        s = fmaf(hv.x, wv.x, s);
        s = fmaf(hv.y, wv.y, s);
        s = fmaf(hv.z, wv.z, s);
        s = fmaf(hv.w, wv.w, s);
    }
    yp[b * nout + o] = s + bias[o];
}

// ---------------- losses ----------------
__global__ void loss_kernel(const float* __restrict__ ypx, const float* __restrict__ ypA,
                            const float* __restrict__ y_x, const float* __restrict__ y_A,
                            float* __restrict__ out) {
    int b = blockIdx.x * 256 + threadIdx.x;
    if (b >= GB) return;
#pragma unroll
    for (int j = 0; j < 2; ++j) {
        float p  = ypx[b * 4 + j];
        float a  = p * p + 1e-7f;
        float mu = ypx[b * 4 + 2 + j];
        float e  = (y_x[b * 2 + j] - mu) / a;
        out[b * 2 + j] = e * e + logf(a);
    }
    float p  = ypA[b * 2 + 0];
    float a  = p * p + 1e-7f;
    float mu = ypA[b * 2 + 1];
    float e  = (y_A[b] - mu) / a;
    out[2 * GB + b] = e * e + logf(a);
}

extern "C" void kernel_launch(void* const* d_in, const int* in_sizes, int n_in,
                              void* d_out, int out_size, void* d_ws, size_t ws_size,
                              hipStream_t stream) {
    const float* x_x     = (const float*)d_in[0];
    const float* y_x     = (const float*)d_in[1];
    const int*   ei_x    = (const int*)d_in[2];
    const int*   batch_x = (const int*)d_in[3];
    const float* x_A     = (const float*)d_in[4];
    const float* y_A     = (const float*)d_in[5];
    const int*   ei_A    = (const int*)d_in[6];
    const int*   batch_A = (const int*)d_in[7];
    const int*   idi_A   = (const int*)d_in[8];
    const int*   idj_A   = (const int*)d_in[9];
    const float* W1r = (const float*)d_in[10];
    const float* W1n = (const float*)d_in[11];
    const float* b1  = (const float*)d_in[12];
    const float* W2r = (const float*)d_in[13];
    const float* W2n = (const float*)d_in[14];
    const float* b2  = (const float*)d_in[15];
    const float* nW1 = (const float*)d_in[16];
    const float* nb1 = (const float*)d_in[17];
    const float* nW2 = (const float*)d_in[18];
    const float* nb2 = (const float*)d_in[19];
    const float* nW3 = (const float*)d_in[20];
    const float* nb3 = (const float*)d_in[21];
    const float* eW1 = (const float*)d_in[22];
    const float* eb1 = (const float*)d_in[23];
    const float* eW2 = (const float*)d_in[24];
    const float* eb2 = (const float*)d_in[25];
    const float* eW3 = (const float*)d_in[26];
    const float* eb3 = (const float*)d_in[27];

    // ---- workspace layout ----
    __bf16* gmh  = (__bf16*)d_ws;                    // GN*256
    __bf16* gml  = gmh + (size_t)GN * 256;           // GN*256
    float*  msg1 = (float*)(gml + (size_t)GN * 256); // 2*GN*2
    float*  rgx  = msg1 + (size_t)2 * GN * 2;        // GB*256
    float*  use  = rgx  + (size_t)GB * 256;          // GB*768
    __bf16* wcat_hi = (__bf16*)(use + (size_t)GB * 768);
    __bf16* wcat_lo = wcat_hi + 65536;
    __bf16* nW1hi = wcat_lo + 65536;
    __bf16* nW1lo = nW1hi + 65536;
    __bf16* nW2hi = nW1lo + 65536;
    __bf16* nW2lo = nW2hi + 131072;
    __bf16* eW1hi = nW2lo + 131072;
    __bf16* eW1lo = eW1hi + 196608;
    __bf16* eW2hi = eW1lo + 196608;
    __bf16* eW2lo = eW2hi + 131072;
    int* rowptr = (int*)(eW2lo + 131072);            // 2*GN
    int* cursor = rowptr + 2 * GN;                   // 2*GN
    int* eidx   = cursor + 2 * GN;                   // 2*GE
    int* csum   = eidx + 2 * GE;                     // 256
    char* wend  = (char*)(csum + 256);
    // aliases into gmh/gml region (dead after sel-GEMM):
    __bf16* h1h = gmh;
    __bf16* h1l = h1h + (size_t)GB * 256;
    float*  h2  = (float*)(h1l + (size_t)GB * 256);
    float*  ypx = h2 + (size_t)GB * 512;
    float*  ypA = ypx + (size_t)GB * 4;

    size_t need = (size_t)(wend - (char*)d_ws);
    if (ws_size < need) return;

    float* out = (float*)d_out;

    // weight prep
    prep_wcat_split<<<256, 256, 0, stream>>>(W2r, W2n, wcat_hi, wcat_lo);
    prep_split<<<256, 256, 0, stream>>>(nW1, nW1hi, nW1lo, 65536);
    prep_split<<<512, 256, 0, stream>>>(nW2, nW2hi, nW2lo, 131072);
    prep_split<<<768, 256, 0, stream>>>(eW1, eW1hi, eW1lo, 196608);
    prep_split<<<512, 256, 0, stream>>>(eW2, eW2hi, eW2lo, 131072);

    // CSR + msg1 for BOTH graphs, fused
    hipMemsetAsync(rowptr, 0, (size_t)2 * GN * sizeof(int), stream);
    deg2_kernel<<<(2 * GE + 255) / 256, 256, 0, stream>>>(ei_x + GE, ei_A + GE, rowptr);
    scan1_kernel<<<2 * NCHUNK, 512, 0, stream>>>(rowptr, csum);
    scan2_kernel<<<2, 128, 0, stream>>>(csum);
    scan3_kernel<<<(2 * GN + 255) / 256, 256, 0, stream>>>(rowptr, cursor, csum);
    fill2_kernel<<<(2 * GE + 255) / 256, 256, 0, stream>>>(ei_x, ei_x + GE, ei_A, ei_A + GE,
                                                           cursor, eidx);
    msg1_kernel<<<(2 * GN + 255) / 256, 256, 0, stream>>>(x_x, x_A, rowptr, cursor, eidx, msg1);

    const int conv2_grid = GN / 64;                 // 3125
    const int sel_grid   = (2 * GB + 63) / 64;      // 313
    const int mlp_mt     = (GB + 63) / 64;          // 157

    for (int g = 0; g < 2; ++g) {
        const float* x = g == 0 ? x_x : x_A;
        const int* rp  = rowptr + g * GN;
        const int* cu  = cursor + g * GN;
        const int* ei  = eidx + (size_t)g * GE;
        const int* bat = g == 0 ? batch_x : batch_A;

        conv1_kernel<<<GN * 128 / 256, 256, 0, stream>>>(x, msg1 + (size_t)g * GN * 2,
                                                         W1r, W1n, b1, gmh, gml);
        msg2_csr_kernel<<<GN / 4, 256, 0, stream>>>(gmh, gml, rp, cu, ei, gmh, gml);

        if (g == 0) {
            hipMemsetAsync(rgx, 0, (size_t)GB * 256 * sizeof(float), stream);
            conv2_gemm<1><<<conv2_grid, 256, 0, stream>>>(
                gmh, gml, wcat_hi, wcat_lo, b2, rgx, 256, GN, bat, nullptr);
        } else {
            hipMemsetAsync(use, 0, (size_t)GB * 768 * sizeof(float), stream);
            conv2_gemm<1><<<conv2_grid, 256, 0, stream>>>(
                gmh, gml, wcat_hi, wcat_lo, b2, use, 768, GN, bat, nullptr);
            conv2_gemm<2><<<sel_grid, 256, 0, stream>>>(
                gmh, gml, wcat_hi, wcat_lo, b2, use, 768, 2 * GB, idi_A, idj_A);
        }
    }

    // node MLP (h1/h2 alias gmh region; gm dead now)
    mfma_gemm2<2, 0, 1><<<mlp_mt, 256, 0, stream>>>(
        rgx, nullptr, nullptr, 256, nW1hi, nW1lo, nb1,
        nullptr, h1h, h1l, 256, GB, 256, 1);
    mfma_gemm2<2, 1, 0><<<mlp_mt * 2, 256, 0, stream>>>(
        nullptr, h1h, h1l, 256, nW2hi, nW2lo, nb2,
        h2, nullptr, nullptr, 512, GB, 256, 2);
    outhead_kernel<<<(GB * 4 + 255) / 256, 256, 0, stream>>>(h2, nW3, nb3, ypx, 4);

    // edge MLP
    mfma_gemm2<2, 0, 1><<<mlp_mt, 256, 0, stream>>>(
        use, nullptr, nullptr, 768, eW1hi, eW1lo, eb1,
        nullptr, h1h, h1l, 256, GB, 768, 1);
    mfma_gemm2<2, 1, 0><<<mlp_mt * 2, 256, 0, stream>>>(
        nullptr, h1h, h1l, 256, eW2hi, eW2lo, eb2,
        h2, nullptr, nullptr, 512, GB, 256, 2);
    outhead_kernel<<<(GB * 2 + 255) / 256, 256, 0, stream>>>(h2, eW3, eb3, ypA, 2);

    loss_kernel<<<(GB + 255) / 256, 256, 0, stream>>>(ypx, ypA, y_x, y_A, out);
}